// Round 4
// baseline (251.337 us; speedup 1.0000x reference)
//
#include <hip/hip_runtime.h>
#include <stdint.h>
#include <math.h>

typedef unsigned short u16;
typedef __bf16 bf16x8 __attribute__((ext_vector_type(8)));
typedef float f32x4 __attribute__((ext_vector_type(4)));

enum { M_SCORE = 1, M_PV = 2 };

// fp32 -> bf16 round-to-nearest-even, bit-level
__device__ __forceinline__ u16 f2bf(float f) {
    union { float f; unsigned int u; } a; a.f = f;
    unsigned int u = a.u;
    u += 0x7FFFu + ((u >> 16) & 1u);
    return (u16)(u >> 16);
}

__device__ __forceinline__ void async_load16(const void* g, void* l) {
    __builtin_amdgcn_global_load_lds(
        (const __attribute__((address_space(1))) void*)g,
        (__attribute__((address_space(3))) void*)l,
        16, 0, 0);
}

// ---------------------------------------------------------------------------
// gemm2: 2-buffer issue-early pipeline (T3 minimum 2-phase, m248v2 family).
// 128x128 tile, 4 waves 2x2, KB=64. Per K-step: stage(t+1 -> buf^1) issued
// FIRST, then compute(buf), then own-vmcnt(0) + one s_barrier. The t+1 loads
// fly under the whole MFMA phase; one barrier/step. Race-free: staging
// targets the buffer whose compute all waves finished one barrier ago.
// Same granule-XOR LDS family as before (verified 0 bank conflicts).
// M_SCORE: Cv = packed E tile base, writes exp2+rowsum (atomics).
// M_PV:    A  = packed E row base (tiles kt=k0>>7), final divide by rowsum.
// ---------------------------------------------------------------------------
template<int MODE>
__device__ __forceinline__ void gemm2(
    const u16* __restrict__ A, const u16* __restrict__ Bt,
    void* __restrict__ Cv, float* __restrict__ rowsum,
    int bm, int bn, int bz, int M, int N, int K, float kfac,
    u16* As, u16* Bs)          // each 2 x 8192 u16 (double-buffered)
{
    constexpr int KB = 64;
    const int tid  = threadIdx.x;
    const int lane = tid & 63;
    const int wv   = tid >> 6;
    const int wm   = wv >> 1;
    const int wn   = wv & 1;

    f32x4 acc[4][4] = {};

    const int rowA0 = bm * 128, rowB0 = bn * 128;
    const int lrow  = lane >> 3;
    const int lslot = lane & 7;
    const int sg    = (lslot ^ lrow) * 8;

    int kEnd = K;
    if (MODE == M_PV) { int ke = (bm + 1) * 128; kEnd = ke < K ? ke : K; }
    const int nt = kEnd >> 6;            // K-steps (KB=64)

    const int lm   = lane & 15;
    const int quad = lane >> 4;
    const int rx   = lm & 7;

    auto stage = [&](int t, int b) {
        const int k0 = t << 6;
        u16* as = As + b * 8192;
        u16* bs = Bs + b * 8192;
        #pragma unroll
        for (int c = 0; c < 4; ++c) {
            const int cc  = wv * 4 + c;
            const int row = cc * 8 + lrow;
            const u16* srcA;
            if (MODE == M_PV)    // packed tri tiles: kt*16384 + row*128 + koff
                srcA = &A[(size_t)(k0 >> 7) * 16384 + (size_t)row * 128 + (k0 & 127) + sg];
            else
                srcA = &A[(size_t)(rowA0 + row) * K + k0 + sg];
            async_load16(srcA, &as[cc * 512 + lane * 8]);
            async_load16(&Bt[(size_t)(rowB0 + row) * K + k0 + sg], &bs[cc * 512 + lane * 8]);
        }
    };

    auto compute = [&](int b) {
        const u16* as = As + b * 8192;
        const u16* bs = Bs + b * 8192;
        #pragma unroll
        for (int h = 0; h < 2; ++h) {
            const int sl = (((h * 4 + quad) ^ rx) * 8);
            bf16x8 af[4], bfr[4];
            #pragma unroll
            for (int i = 0; i < 4; ++i)
                af[i] = *reinterpret_cast<const bf16x8*>(
                    &as[(wm * 64 + i * 16 + lm) * KB + sl]);
            #pragma unroll
            for (int j = 0; j < 4; ++j)
                bfr[j] = *reinterpret_cast<const bf16x8*>(
                    &bs[(wn * 64 + j * 16 + lm) * KB + sl]);
            #pragma unroll
            for (int i = 0; i < 4; ++i)
                #pragma unroll
                for (int j = 0; j < 4; ++j)
                    acc[i][j] = __builtin_amdgcn_mfma_f32_16x16x32_bf16(af[i], bfr[j], acc[i][j], 0, 0, 0);
        }
    };

    // prologue: tile 0 (cold drain, 1 of nt steps)
    stage(0, 0);
    asm volatile("s_waitcnt vmcnt(0)" ::: "memory");
    __builtin_amdgcn_s_barrier();

    int cb = 0;
    #pragma unroll 1
    for (int t = 0; t < nt - 1; ++t) {
        stage(t + 1, cb ^ 1);            // issue early: flies under compute
        compute(cb);
        asm volatile("s_waitcnt vmcnt(0)" ::: "memory");
        __builtin_amdgcn_s_barrier();
        cb ^= 1;
    }
    compute(cb);

    // Epilogue. C/D layout (m89-verified): col = lane&15, row = quad*4 + reg.
    if (MODE == M_SCORE) {
        u16* E = (u16*)Cv;               // packed 128x128 tile, row-major
        float rs[4][4];
        #pragma unroll
        for (int i = 0; i < 4; ++i)
            #pragma unroll
            for (int g = 0; g < 4; ++g) rs[i][g] = 0.f;
        #pragma unroll
        for (int i = 0; i < 4; ++i)
            #pragma unroll
            for (int j = 0; j < 4; ++j) {
                const int rl = wm * 64 + i * 16 + quad * 4;   // local row
                const int cl = wn * 64 + j * 16 + lm;         // local col
                const int c  = rowB0 + cl;                    // global col
                #pragma unroll
                for (int g = 0; g < 4; ++g) {
                    const int r = rowA0 + rl + g;             // global row
                    float e = (c <= r) ? exp2f(acc[i][j][g] * kfac) : 0.f;
                    E[(size_t)(rl + g) * 128 + cl] = f2bf(e);
                    rs[i][g] += e;
                }
            }
        #pragma unroll
        for (int i = 0; i < 4; ++i)
            #pragma unroll
            for (int g = 0; g < 4; ++g) {
                float v = rs[i][g];
                v += __shfl_xor(v, 1); v += __shfl_xor(v, 2);
                v += __shfl_xor(v, 4); v += __shfl_xor(v, 8);
                rs[i][g] = v;
            }
        if (lm == 0) {
            #pragma unroll
            for (int i = 0; i < 4; ++i)
                #pragma unroll
                for (int g = 0; g < 4; ++g) {
                    const int r = rowA0 + wm * 64 + i * 16 + quad * 4 + g;
                    atomicAdd(&rowsum[(size_t)bz * M + r], rs[i][g]);
                }
        }
    } else {  // M_PV
        float* C = (float*)Cv + (size_t)bz * ((size_t)M * N);
        #pragma unroll
        for (int i = 0; i < 4; ++i) {
            const int r0 = rowA0 + wm * 64 + i * 16 + quad * 4;
            float inv[4];
            #pragma unroll
            for (int g = 0; g < 4; ++g)
                inv[g] = 1.f / rowsum[(size_t)bz * M + r0 + g];
            #pragma unroll
            for (int j = 0; j < 4; ++j) {
                const int c0 = rowB0 + wn * 64 + j * 16 + lm;
                #pragma unroll
                for (int g = 0; g < 4; ++g)
                    C[(size_t)(r0 + g) * N + c0] = acc[i][j][g] * inv[g];
            }
        }
    }
}

// ---------------------------------------------------------------------------
// k_qkv2: counted-vmcnt triple-buffered GEMM (T4). 128x256 tile, 8 waves
// (2M x 4N), wave tile 64x64, KB=64. 3 LDS buffers of 48KB (A 16KB + B 32KB).
// Loads never drained to 0 in the main loop.
// ---------------------------------------------------------------------------
__global__ __launch_bounds__(512, 2)
void k_qkv2(const u16* __restrict__ Xb, const u16* __restrict__ Wt,
            u16* __restrict__ Q, int M, int N, int K)
{
    extern __shared__ __attribute__((aligned(16))) u16 S[];
    const int tid  = threadIdx.x;
    const int lane = tid & 63;
    const int wv   = tid >> 6;           // 0..7
    const int wm   = wv >> 2;            // 0..1  (M half)
    const int wn   = wv & 3;             // 0..3  (N quarter)
    const int bn   = blockIdx.x;         // N/256
    const int bm   = blockIdx.y;         // M/128
    const int rowA0 = bm * 128, rowB0 = bn * 256;

    const int lrow  = lane >> 3;
    const int lslot = lane & 7;
    const int sg    = (lslot ^ lrow) * 8;
    const int lm    = lane & 15;
    const int quad  = lane >> 4;
    const int rx    = lm & 7;

    f32x4 acc[4][4] = {};

    const int nt = K >> 6;               // K/64 tiles (=16)

    auto stage = [&](int t, int b) {
        u16* As = S + b * 24576;
        u16* Bs = As + 8192;
        const int k0 = t << 6;
        #pragma unroll
        for (int c = 0; c < 2; ++c) {
            const int cc  = wv * 2 + c;
            const int row = cc * 8 + lrow;
            async_load16(&Xb[(size_t)(rowA0 + row) * K + k0 + sg], &As[cc * 512 + lane * 8]);
        }
        #pragma unroll
        for (int c = 0; c < 4; ++c) {
            const int cc  = wv * 4 + c;
            const int row = cc * 8 + lrow;
            async_load16(&Wt[(size_t)(rowB0 + row) * K + k0 + sg], &Bs[cc * 512 + lane * 8]);
        }
    };

    auto compute = [&](int b) {
        const u16* As = S + b * 24576;
        const u16* Bs = As + 8192;
        #pragma unroll
        for (int h = 0; h < 2; ++h) {
            const int sl = (((h * 4 + quad) ^ rx) * 8);
            bf16x8 af[4], bfr[4];
            #pragma unroll
            for (int i = 0; i < 4; ++i)
                af[i] = *reinterpret_cast<const bf16x8*>(
                    &As[(wm * 64 + i * 16 + lm) * 64 + sl]);
            #pragma unroll
            for (int j = 0; j < 4; ++j)
                bfr[j] = *reinterpret_cast<const bf16x8*>(
                    &Bs[(wn * 64 + j * 16 + lm) * 64 + sl]);
            #pragma unroll
            for (int i = 0; i < 4; ++i)
                #pragma unroll
                for (int j = 0; j < 4; ++j)
                    acc[i][j] = __builtin_amdgcn_mfma_f32_16x16x32_bf16(af[i], bfr[j], acc[i][j], 0, 0, 0);
        }
    };

    stage(0, 0);
    stage(1, 1);
    asm volatile("s_waitcnt vmcnt(6)" ::: "memory");
    __builtin_amdgcn_s_barrier();

    int cb = 0;
    #pragma unroll 1
    for (int t = 0; t < nt - 2; ++t) {
        int sb = cb + 2; if (sb >= 3) sb -= 3;
        stage(t + 2, sb);
        compute(cb);
        asm volatile("s_waitcnt vmcnt(6)" ::: "memory");
        __builtin_amdgcn_s_barrier();
        if (++cb == 3) cb = 0;
    }
    compute(cb);
    asm volatile("s_waitcnt vmcnt(0)" ::: "memory");
    __builtin_amdgcn_s_barrier();
    if (++cb == 3) cb = 0;
    compute(cb);

    u16* C = Q + (size_t)(bn >> 2) * ((size_t)M * 1024);   // which of Q/K/V
    const int cbase = (rowB0 & 1023) + wn * 64;
    #pragma unroll
    for (int i = 0; i < 4; ++i)
        #pragma unroll
        for (int j = 0; j < 4; ++j) {
            const int r0 = rowA0 + wm * 64 + i * 16 + quad * 4;
            const int c0 = cbase + j * 16 + lm;
            #pragma unroll
            for (int g = 0; g < 4; ++g)
                C[(size_t)(r0 + g) * 1024 + c0] = f2bf(acc[i][j][g]);
        }
}

// S (tri 128x128 blocks, packed E out) + V-transpose (tail-fill blocks).
__global__ __launch_bounds__(256)
void k_score_vt(const u16* __restrict__ Q, const u16* __restrict__ Kb,
                u16* __restrict__ Epk, float* __restrict__ rowsum,
                const u16* __restrict__ Vb, u16* __restrict__ Vt,
                int T, int D, float kfac, int nTri)
{
    __shared__ __attribute__((aligned(16))) u16 As[2 * 128 * 64];
    __shared__ __attribute__((aligned(16))) u16 Bs[2 * 128 * 64];
    __shared__ u16 tt[32][33];
    const int bz = blockIdx.z;

    if ((int)blockIdx.x < nTri) {
        // triangular decode: idx = bm*(bm+1)/2 + bn, bn <= bm
        const int idx = blockIdx.x;
        int bm = (int)((sqrtf(8.f * (float)idx + 1.f) - 1.f) * 0.5f);
        while (bm * (bm + 1) / 2 > idx) --bm;
        while ((bm + 1) * (bm + 2) / 2 <= idx) ++bm;
        const int bn = idx - bm * (bm + 1) / 2;
        u16* Etile = Epk + ((size_t)bz * nTri + idx) * 16384;
        gemm2<M_SCORE>(Q + (size_t)bz * T * D, Kb + (size_t)bz * T * D,
                       Etile, rowsum, bm, bn, bz, T, T, D, kfac, As, Bs);
    } else {
        const int t  = blockIdx.x - nTri;
        const int cx = t & 31;          // D/32 tiles
        const int cy = t >> 5;          // T/32 tiles
        const u16* V = Vb + (size_t)bz * T * D;
        u16*      Vo = Vt + (size_t)bz * D * T;
        const int c0 = cx * 32, r0 = cy * 32;
        const int tx = threadIdx.x & 31, ty = threadIdx.x >> 5;
        #pragma unroll
        for (int s = 0; s < 32; s += 8)
            tt[ty + s][tx] = V[(size_t)(r0 + ty + s) * D + c0 + tx];
        __syncthreads();
        #pragma unroll
        for (int s = 0; s < 32; s += 8)
            Vo[(size_t)(c0 + ty + s) * T + r0 + tx] = tt[tx][ty + s];
    }
}

// PV: 128x128 tiles, heavy rows (large bm) dispatched FIRST (LPT scheduling)
__global__ __launch_bounds__(256)
void k_pv(const u16* __restrict__ Epk, const u16* __restrict__ Vt,
          float* __restrict__ out, const float* __restrict__ rowsum,
          int T, int D, int nTri)
{
    __shared__ __attribute__((aligned(16))) u16 As[2 * 128 * 64];
    __shared__ __attribute__((aligned(16))) u16 Bs[2 * 128 * 64];
    const int bz = blockIdx.z;
    const int bm = (gridDim.y - 1) - blockIdx.y;   // heavy-first
    const u16* Arow = Epk + ((size_t)bz * nTri + (size_t)bm * (bm + 1) / 2) * 16384;
    gemm2<M_PV>(Arow, Vt + (size_t)bz * D * T,
                out, (float*)rowsum, bm, blockIdx.x, bz,
                T, D, T, 0.f, As, Bs);
}

// prep: cast_x (blocks [0,nCX)) + W transpose-cast ([nCX,nCX+nW)) + RS zero
__global__ __launch_bounds__(256)
void k_prep(const float* __restrict__ x,
            const float* __restrict__ W0, const float* __restrict__ W1,
            const float* __restrict__ W2,
            u16* __restrict__ Xb, u16* __restrict__ Wt, float* __restrict__ RS,
            int D, int nCX, int nW)
{
    const int bx = blockIdx.x;
    if (bx < nCX) {
        long long i = ((long long)bx * 256 + threadIdx.x) * 8;
        const float4 a = *(const float4*)(x + i);
        const float4 b = *(const float4*)(x + i + 4);
        union { u16 u[8]; float4 v; } r;
        r.u[0] = f2bf(a.x); r.u[1] = f2bf(a.y); r.u[2] = f2bf(a.z); r.u[3] = f2bf(a.w);
        r.u[4] = f2bf(b.x); r.u[5] = f2bf(b.y); r.u[6] = f2bf(b.z); r.u[7] = f2bf(b.w);
        *(float4*)(Xb + i) = r.v;
    } else if (bx < nCX + nW) {
        __shared__ u16 t[32][33];
        const int w  = bx - nCX;
        const int z  = w >> 10;                 // 1024 tiles per matrix (32x32)
        const int rm = w & 1023;
        const float* W = z == 0 ? W0 : (z == 1 ? W1 : W2);
        u16* dst = Wt + (size_t)z * D * D;
        const int c0 = (rm & 31) * 32, r0 = (rm >> 5) * 32;
        const int tx = threadIdx.x & 31, ty = threadIdx.x >> 5;
        #pragma unroll
        for (int s = 0; s < 32; s += 8)
            t[ty + s][tx] = f2bf(W[(size_t)(r0 + ty + s) * D + c0 + tx]);
        __syncthreads();
        #pragma unroll
        for (int s = 0; s < 32; s += 8)
            dst[(size_t)(c0 + ty + s) * D + r0 + tx] = t[tx][ty + s];
    } else {
        const int t = bx - nCX - nW;
        ((float4*)RS)[t * 256 + threadIdx.x] = float4{0.f, 0.f, 0.f, 0.f};
    }
}

extern "C" void kernel_launch(void* const* d_in, const int* in_sizes, int n_in,
                              void* d_out, int out_size, void* d_ws, size_t ws_size,
                              hipStream_t stream)
{
    const int B = 4, T = 2048, D = 1024;
    const float* x  = (const float*)d_in[0];
    const float* Wq = (const float*)d_in[1];
    const float* Wk = (const float*)d_in[2];
    const float* Wv = (const float*)d_in[3];
    float* out = (float*)d_out;

    // Workspace layout (86 MB + 32 KB):
    //   [0,16M)   Xb   bf16 x        (dead after k_qkv2)
    //   [16,22M)  Wt   3 x W^T bf16  (dead after k_qkv2)
    //   [0,17.8M) Epk  packed tri E, 4 x 136 tiles x 32KB  (aliases Xb/Wt)
    //   [22,38M)  Q    [38,54M) K    [54,70M) V    [70,86M) Vt
    //   [86M,+32K) RS  rowsum fp32
    const size_t nX = (size_t)B * T * D;
    u16* Xb  = (u16*)d_ws;
    u16* Wt  = Xb + nX;
    u16* Epk = (u16*)d_ws;                         // alias over Xb+Wt
    u16* Q   = Wt + 3 * (size_t)D * D;
    u16* Kb  = Q + nX;
    u16* Vb  = Kb + nX;
    u16* Vt  = Vb + nX;
    float* RS = (float*)(Vt + nX);

    const float kfac = 1.4426950408889634f / 32.0f;  // log2(e)/sqrt(d_out)
    const int nTri128 = 136;  // sum_{bm=0..15} (bm+1), 128x128 tri tiles
    const int nCX = (int)(nX / (8 * 256));           // 4096 cast blocks
    const int nW  = 3 * (D / 32) * (D / 32);         // 3072 W-transpose blocks
    const int nRS = (B * T) / (4 * 256);             // 8 RS-zero blocks

    static bool attr_done = false;
    if (!attr_done) {
        (void)hipFuncSetAttribute((const void*)k_qkv2,
                                  hipFuncAttributeMaxDynamicSharedMemorySize,
                                  147456);
        attr_done = true;
    }

    // 1. prep: x-cast + W-transpose-cast + RS zero
    k_prep<<<dim3(nCX + nW + nRS), 256, 0, stream>>>(
        x, Wq, Wk, Wv, Xb, Wt, RS, D, nCX, nW);
    // 2. merged QKV projection, counted-vmcnt triple-buffer
    k_qkv2<<<dim3(3 * D / 256, (B * T) / 128), 512, 147456, stream>>>(
        Xb, Wt, Q, B * T, 3 * D, D);
    // 3. S -> packed tri E (136 blocks/batch) + V-transpose tail (2048/batch)
    k_score_vt<<<dim3(nTri128 + (D / 32) * (T / 32), 1, B), 256, 0, stream>>>(
        Q, Kb, Epk, RS, Vb, Vt, T, D, kfac, nTri128);
    // 4. PV from packed E, heavy-first
    k_pv<<<dim3(D / 128, T / 128, B), 256, 0, stream>>>(
        Epk, Vt, out, RS, T, D, nTri128);
}

// Round 5
// 233.503 us; speedup vs baseline: 1.0764x; 1.0764x over previous
//
#include <hip/hip_runtime.h>
#include <stdint.h>
#include <math.h>

typedef unsigned short u16;
typedef __bf16 bf16x8 __attribute__((ext_vector_type(8)));
typedef float f32x4 __attribute__((ext_vector_type(4)));

enum { M_SCORE = 1, M_PV = 2 };

// fp32 -> bf16 round-to-nearest-even, bit-level
__device__ __forceinline__ u16 f2bf(float f) {
    union { float f; unsigned int u; } a; a.f = f;
    unsigned int u = a.u;
    u += 0x7FFFu + ((u >> 16) & 1u);
    return (u16)(u >> 16);
}

__device__ __forceinline__ void async_load16(const void* g, void* l) {
    __builtin_amdgcn_global_load_lds(
        (const __attribute__((address_space(1))) void*)g,
        (__attribute__((address_space(3))) void*)l,
        16, 0, 0);
}

// ---------------------------------------------------------------------------
// gemm_core (R0 structure): TBM x 128 tile, KB=64/iter, 4 waves 2x2,
// 2-barrier loop, 24KB LDS @ TBM=64 -> ~6 blocks/CU (score/pv are
// latency-bound; TLP is the lever — R1/R4 occupancy-reducing variants
// measured neutral-to-worse).
// LDS granule (row,g) at slot g^(row&7); staging permutes the *global*
// granule per lane (verified family: 0 bank conflicts).
// Packed E: 136 lower-tri 128x128 tiles per batch, tile tri(bm128)+bn128.
// M_SCORE: Cv = packed tile base; local row = (rowA0&127)+rl.
// M_PV:    A  = packed row base for bm128; k-tile = k0>>7.
// ---------------------------------------------------------------------------
template<int MODE, int TBM>
__device__ __forceinline__ void gemm_core(
    const u16* __restrict__ A, const u16* __restrict__ Bt,
    void* __restrict__ Cv, float* __restrict__ rowsum,
    int bm, int bn, int bz, int M, int N, int K, float kfac,
    u16* As, u16* Bs)
{
    constexpr int KB  = 64;
    constexpr int NI  = TBM / 32;        // m-frags per wave
    constexpr int ACH = TBM / 32;        // A staging chunks per wave
    constexpr int BCH = 4;               // B staging chunks per wave

    const int tid  = threadIdx.x;
    const int lane = tid & 63;
    const int wv   = tid >> 6;
    const int wm   = wv >> 1;
    const int wn   = wv & 1;

    f32x4 acc[NI][4] = {};

    const int rowA0 = bm * TBM, rowB0 = bn * 128;
    const int lrow  = lane >> 3;
    const int lslot = lane & 7;
    const int sg    = (lslot ^ lrow) * 8;

    int kEnd = K;
    if (MODE == M_PV) { int ke = (bm + 1) * TBM; kEnd = ke < K ? ke : K; }

    const int lm   = lane & 15;
    const int quad = lane >> 4;
    const int rx   = lm & 7;

    for (int k0 = 0; k0 < kEnd; k0 += KB) {
        #pragma unroll
        for (int c = 0; c < ACH; ++c) {
            const int cc  = wv * ACH + c;
            const int row = cc * 8 + lrow;
            const u16* src;
            if (MODE == M_PV)   // packed tri tiles: kt*16384 + localrow*128 + koff
                src = &A[(size_t)(k0 >> 7) * 16384
                         + (size_t)((rowA0 & 127) + row) * 128 + (k0 & 127) + sg];
            else
                src = &A[(size_t)(rowA0 + row) * K + k0 + sg];
            async_load16(src, &As[cc * 512 + lane * 8]);
        }
        #pragma unroll
        for (int c = 0; c < BCH; ++c) {
            const int cc  = wv * BCH + c;
            const int row = cc * 8 + lrow;
            async_load16(&Bt[(size_t)(rowB0 + row) * K + k0 + sg], &Bs[cc * 512 + lane * 8]);
        }
        __syncthreads();

        #pragma unroll
        for (int h = 0; h < 2; ++h) {
            const int sl = (((h * 4 + quad) ^ rx) * 8);
            bf16x8 af[NI], bfr[4];
            #pragma unroll
            for (int i = 0; i < NI; ++i)
                af[i] = *reinterpret_cast<const bf16x8*>(
                    &As[(wm * (TBM / 2) + i * 16 + lm) * KB + sl]);
            #pragma unroll
            for (int j = 0; j < 4; ++j)
                bfr[j] = *reinterpret_cast<const bf16x8*>(
                    &Bs[(wn * 64 + j * 16 + lm) * KB + sl]);
            #pragma unroll
            for (int i = 0; i < NI; ++i)
                #pragma unroll
                for (int j = 0; j < 4; ++j)
                    acc[i][j] = __builtin_amdgcn_mfma_f32_16x16x32_bf16(af[i], bfr[j], acc[i][j], 0, 0, 0);
        }
        __syncthreads();
    }

    // Epilogue. C/D layout (m89-verified): col = lane&15, row = quad*4 + reg.
    if (MODE == M_SCORE) {
        u16* E = (u16*)Cv;               // packed 128x128 tile, row-major
        const int rbase = rowA0 & 127;   // row offset inside packed tile
        float rs[NI][4];
        #pragma unroll
        for (int i = 0; i < NI; ++i)
            #pragma unroll
            for (int g = 0; g < 4; ++g) rs[i][g] = 0.f;
        #pragma unroll
        for (int i = 0; i < NI; ++i)
            #pragma unroll
            for (int j = 0; j < 4; ++j) {
                const int rl = wm * (TBM / 2) + i * 16 + quad * 4;   // local row
                const int cl = wn * 64 + j * 16 + lm;                // local col
                const int c  = rowB0 + cl;                           // global col
                #pragma unroll
                for (int g = 0; g < 4; ++g) {
                    const int r = rowA0 + rl + g;                    // global row
                    float e = (c <= r) ? exp2f(acc[i][j][g] * kfac) : 0.f;
                    E[(size_t)(rbase + rl + g) * 128 + cl] = f2bf(e);
                    rs[i][g] += e;
                }
            }
        #pragma unroll
        for (int i = 0; i < NI; ++i)
            #pragma unroll
            for (int g = 0; g < 4; ++g) {
                float v = rs[i][g];
                v += __shfl_xor(v, 1); v += __shfl_xor(v, 2);
                v += __shfl_xor(v, 4); v += __shfl_xor(v, 8);
                rs[i][g] = v;
            }
        if (lm == 0) {
            #pragma unroll
            for (int i = 0; i < NI; ++i)
                #pragma unroll
                for (int g = 0; g < 4; ++g) {
                    const int r = rowA0 + wm * (TBM / 2) + i * 16 + quad * 4 + g;
                    atomicAdd(&rowsum[(size_t)bz * M + r], rs[i][g]);
                }
        }
    } else {  // M_PV
        float* C = (float*)Cv + (size_t)bz * ((size_t)M * N);
        #pragma unroll
        for (int i = 0; i < NI; ++i) {
            const int r0 = rowA0 + wm * (TBM / 2) + i * 16 + quad * 4;
            float inv[4];
            #pragma unroll
            for (int g = 0; g < 4; ++g)
                inv[g] = 1.f / rowsum[(size_t)bz * M + r0 + g];
            #pragma unroll
            for (int j = 0; j < 4; ++j) {
                const int c0 = rowB0 + wn * 64 + j * 16 + lm;
                #pragma unroll
                for (int g = 0; g < 4; ++g)
                    C[(size_t)(r0 + g) * N + c0] = acc[i][j][g] * inv[g];
            }
        }
    }
}

// ---------------------------------------------------------------------------
// k_qkv2: counted-vmcnt triple-buffered GEMM (T4). 128x256 tile, 8 waves
// (2M x 4N), wave tile 64x64, KB=64. 3 LDS buffers of 48KB (A 16KB + B 32KB).
// Loads never drained to 0 in the main loop. Measured 61 us (vs 67 for the
// 2-barrier 128x128 version) — kept.
// ---------------------------------------------------------------------------
__global__ __launch_bounds__(512, 2)
void k_qkv2(const u16* __restrict__ Xb, const u16* __restrict__ Wt,
            u16* __restrict__ Q, int M, int N, int K)
{
    extern __shared__ __attribute__((aligned(16))) u16 S[];
    const int tid  = threadIdx.x;
    const int lane = tid & 63;
    const int wv   = tid >> 6;           // 0..7
    const int wm   = wv >> 2;            // 0..1  (M half)
    const int wn   = wv & 3;             // 0..3  (N quarter)
    const int bn   = blockIdx.x;         // N/256
    const int bm   = blockIdx.y;         // M/128
    const int rowA0 = bm * 128, rowB0 = bn * 256;

    const int lrow  = lane >> 3;
    const int lslot = lane & 7;
    const int sg    = (lslot ^ lrow) * 8;
    const int lm    = lane & 15;
    const int quad  = lane >> 4;
    const int rx    = lm & 7;

    f32x4 acc[4][4] = {};

    const int nt = K >> 6;               // K/64 tiles (=16)

    auto stage = [&](int t, int b) {
        u16* As = S + b * 24576;
        u16* Bs = As + 8192;
        const int k0 = t << 6;
        #pragma unroll
        for (int c = 0; c < 2; ++c) {
            const int cc  = wv * 2 + c;
            const int row = cc * 8 + lrow;
            async_load16(&Xb[(size_t)(rowA0 + row) * K + k0 + sg], &As[cc * 512 + lane * 8]);
        }
        #pragma unroll
        for (int c = 0; c < 4; ++c) {
            const int cc  = wv * 4 + c;
            const int row = cc * 8 + lrow;
            async_load16(&Wt[(size_t)(rowB0 + row) * K + k0 + sg], &Bs[cc * 512 + lane * 8]);
        }
    };

    auto compute = [&](int b) {
        const u16* As = S + b * 24576;
        const u16* Bs = As + 8192;
        #pragma unroll
        for (int h = 0; h < 2; ++h) {
            const int sl = (((h * 4 + quad) ^ rx) * 8);
            bf16x8 af[4], bfr[4];
            #pragma unroll
            for (int i = 0; i < 4; ++i)
                af[i] = *reinterpret_cast<const bf16x8*>(
                    &As[(wm * 64 + i * 16 + lm) * 64 + sl]);
            #pragma unroll
            for (int j = 0; j < 4; ++j)
                bfr[j] = *reinterpret_cast<const bf16x8*>(
                    &Bs[(wn * 64 + j * 16 + lm) * 64 + sl]);
            #pragma unroll
            for (int i = 0; i < 4; ++i)
                #pragma unroll
                for (int j = 0; j < 4; ++j)
                    acc[i][j] = __builtin_amdgcn_mfma_f32_16x16x32_bf16(af[i], bfr[j], acc[i][j], 0, 0, 0);
        }
    };

    stage(0, 0);
    stage(1, 1);
    asm volatile("s_waitcnt vmcnt(6)" ::: "memory");
    __builtin_amdgcn_s_barrier();

    int cb = 0;
    #pragma unroll 1
    for (int t = 0; t < nt - 2; ++t) {
        int sb = cb + 2; if (sb >= 3) sb -= 3;
        stage(t + 2, sb);
        compute(cb);
        asm volatile("s_waitcnt vmcnt(6)" ::: "memory");
        __builtin_amdgcn_s_barrier();
        if (++cb == 3) cb = 0;
    }
    compute(cb);
    asm volatile("s_waitcnt vmcnt(0)" ::: "memory");
    __builtin_amdgcn_s_barrier();
    if (++cb == 3) cb = 0;
    compute(cb);

    u16* C = Q + (size_t)(bn >> 2) * ((size_t)M * 1024);   // which of Q/K/V
    const int cbase = (rowB0 & 1023) + wn * 64;
    #pragma unroll
    for (int i = 0; i < 4; ++i)
        #pragma unroll
        for (int j = 0; j < 4; ++j) {
            const int r0 = rowA0 + wm * 64 + i * 16 + quad * 4;
            const int c0 = cbase + j * 16 + lm;
            #pragma unroll
            for (int g = 0; g < 4; ++g)
                C[(size_t)(r0 + g) * 1024 + c0] = f2bf(acc[i][j][g]);
        }
}

// S (tri 64x128 blocks, packed E out) + V-transpose (tail-fill blocks).
// Blocks [0, nTri): E = exp2(kfac * Q K^T) causal + rowsum.
// Blocks [nTri, nTri+2048): 32x32 transpose tiles of V -> Vt[b][c][t].
__global__ __launch_bounds__(256)
void k_score_vt(const u16* __restrict__ Q, const u16* __restrict__ Kb,
                u16* __restrict__ Epk, float* __restrict__ rowsum,
                const u16* __restrict__ Vb, u16* __restrict__ Vt,
                int T, int D, float kfac, int nTri)
{
    __shared__ __attribute__((aligned(16))) u16 As[64 * 64];
    __shared__ __attribute__((aligned(16))) u16 Bs[128 * 64];
    __shared__ u16 tt[32][33];
    const int bz = blockIdx.z;

    if ((int)blockIdx.x < nTri) {
        // 64-row tri decode (R0-verified): covers bn <= bm/2
        const int idx = blockIdx.x;
        int w = (int)sqrtf((float)idx + 0.5f);
        while (w * w > idx) --w;
        while ((w + 1) * (w + 1) <= idx) ++w;
        int bm, bn;
        if (idx < w * w + w) { bm = 2 * w - 1; bn = idx - w * w; }
        else                 { bm = 2 * w;     bn = idx - (w * w + w); }
        // packed tile: bm128 = bm>>1; tile index = tri(bm128) + bn
        const int bm128 = bm >> 1;
        const int tile  = bm128 * (bm128 + 1) / 2 + bn;
        u16* Etile = Epk + ((size_t)bz * 136 + tile) * 16384;
        gemm_core<M_SCORE, 64>(Q + (size_t)bz * T * D, Kb + (size_t)bz * T * D,
                               Etile, rowsum, bm, bn, bz, T, T, D, kfac, As, Bs);
    } else {
        const int t  = blockIdx.x - nTri;
        const int cx = t & 31;          // D/32 tiles
        const int cy = t >> 5;          // T/32 tiles
        const u16* V = Vb + (size_t)bz * T * D;
        u16*      Vo = Vt + (size_t)bz * D * T;
        const int c0 = cx * 32, r0 = cy * 32;
        const int tx = threadIdx.x & 31, ty = threadIdx.x >> 5;
        #pragma unroll
        for (int s = 0; s < 32; s += 8)
            tt[ty + s][tx] = V[(size_t)(r0 + ty + s) * D + c0 + tx];
        __syncthreads();
        #pragma unroll
        for (int s = 0; s < 32; s += 8)
            Vo[(size_t)(c0 + ty + s) * T + r0 + tx] = tt[tx][ty + s];
    }
}

// PV: 64x128 tiles, heavy rows (large bm) dispatched FIRST (LPT scheduling)
__global__ __launch_bounds__(256)
void k_pv(const u16* __restrict__ Epk, const u16* __restrict__ Vt,
          float* __restrict__ out, const float* __restrict__ rowsum,
          int T, int D)
{
    __shared__ __attribute__((aligned(16))) u16 As[64 * 64];
    __shared__ __attribute__((aligned(16))) u16 Bs[128 * 64];
    const int bz = blockIdx.z;
    const int bm = (gridDim.y - 1) - blockIdx.y;   // 64-row index, heavy-first
    const int bm128 = bm >> 1;
    const u16* Arow = Epk + ((size_t)bz * 136 + (size_t)bm128 * (bm128 + 1) / 2) * 16384;
    gemm_core<M_PV, 64>(Arow, Vt + (size_t)bz * D * T,
                        out, (float*)rowsum, bm, blockIdx.x, bz,
                        T, D, T, 0.f, As, Bs);
}

// prep: cast_x (blocks [0,nCX)) + W transpose-cast ([nCX,nCX+nW)) + RS zero
__global__ __launch_bounds__(256)
void k_prep(const float* __restrict__ x,
            const float* __restrict__ W0, const float* __restrict__ W1,
            const float* __restrict__ W2,
            u16* __restrict__ Xb, u16* __restrict__ Wt, float* __restrict__ RS,
            int D, int nCX, int nW)
{
    const int bx = blockIdx.x;
    if (bx < nCX) {
        long long i = ((long long)bx * 256 + threadIdx.x) * 8;
        const float4 a = *(const float4*)(x + i);
        const float4 b = *(const float4*)(x + i + 4);
        union { u16 u[8]; float4 v; } r;
        r.u[0] = f2bf(a.x); r.u[1] = f2bf(a.y); r.u[2] = f2bf(a.z); r.u[3] = f2bf(a.w);
        r.u[4] = f2bf(b.x); r.u[5] = f2bf(b.y); r.u[6] = f2bf(b.z); r.u[7] = f2bf(b.w);
        *(float4*)(Xb + i) = r.v;
    } else if (bx < nCX + nW) {
        __shared__ u16 t[32][33];
        const int w  = bx - nCX;
        const int z  = w >> 10;                 // 1024 tiles per matrix (32x32)
        const int rm = w & 1023;
        const float* W = z == 0 ? W0 : (z == 1 ? W1 : W2);
        u16* dst = Wt + (size_t)z * D * D;
        const int c0 = (rm & 31) * 32, r0 = (rm >> 5) * 32;
        const int tx = threadIdx.x & 31, ty = threadIdx.x >> 5;
        #pragma unroll
        for (int s = 0; s < 32; s += 8)
            t[ty + s][tx] = f2bf(W[(size_t)(r0 + ty + s) * D + c0 + tx]);
        __syncthreads();
        #pragma unroll
        for (int s = 0; s < 32; s += 8)
            dst[(size_t)(c0 + ty + s) * D + r0 + tx] = t[tx][ty + s];
    } else {
        const int t = bx - nCX - nW;
        ((float4*)RS)[t * 256 + threadIdx.x] = float4{0.f, 0.f, 0.f, 0.f};
    }
}

extern "C" void kernel_launch(void* const* d_in, const int* in_sizes, int n_in,
                              void* d_out, int out_size, void* d_ws, size_t ws_size,
                              hipStream_t stream)
{
    const int B = 4, T = 2048, D = 1024;
    const float* x  = (const float*)d_in[0];
    const float* Wq = (const float*)d_in[1];
    const float* Wk = (const float*)d_in[2];
    const float* Wv = (const float*)d_in[3];
    float* out = (float*)d_out;

    // Workspace layout (86 MB + 32 KB):
    //   [0,16M)   Xb   bf16 x        (dead after k_qkv2)
    //   [16,22M)  Wt   3 x W^T bf16  (dead after k_qkv2)
    //   [0,17.8M) Epk  packed tri E, 4 x 136 tiles x 32KB  (aliases Xb/Wt)
    //   [22,38M)  Q    [38,54M) K    [54,70M) V    [70,86M) Vt
    //   [86M,+32K) RS  rowsum fp32
    const size_t nX = (size_t)B * T * D;
    u16* Xb  = (u16*)d_ws;
    u16* Wt  = Xb + nX;
    u16* Epk = (u16*)d_ws;                         // alias over Xb+Wt
    u16* Q   = Wt + 3 * (size_t)D * D;
    u16* Kb  = Q + nX;
    u16* Vb  = Kb + nX;
    u16* Vt  = Vb + nX;
    float* RS = (float*)(Vt + nX);

    const float kfac = 1.4426950408889634f / 32.0f;  // log2(e)/sqrt(d_out)
    const int nTri64 = 272;   // sum_{bm=0..31} (bm/2 + 1), 64-row tri tiles
    const int nCX = (int)(nX / (8 * 256));           // 4096 cast blocks
    const int nW  = 3 * (D / 32) * (D / 32);         // 3072 W-transpose blocks
    const int nRS = (B * T) / (4 * 256);             // 8 RS-zero blocks

    static bool attr_done = false;
    if (!attr_done) {
        (void)hipFuncSetAttribute((const void*)k_qkv2,
                                  hipFuncAttributeMaxDynamicSharedMemorySize,
                                  147456);
        attr_done = true;
    }

    // 1. prep: x-cast + W-transpose-cast + RS zero
    k_prep<<<dim3(nCX + nW + nRS), 256, 0, stream>>>(
        x, Wq, Wk, Wv, Xb, Wt, RS, D, nCX, nW);
    // 2. merged QKV projection, counted-vmcnt triple-buffer
    k_qkv2<<<dim3(3 * D / 256, (B * T) / 128), 512, 147456, stream>>>(
        Xb, Wt, Q, B * T, 3 * D, D);
    // 3. S -> packed tri E (272 blocks/batch, 64-row) + V-transpose tail
    k_score_vt<<<dim3(nTri64 + (D / 32) * (T / 32), 1, B), 256, 0, stream>>>(
        Q, Kb, Epk, RS, Vb, Vt, T, D, kfac, nTri64);
    // 4. PV from packed E, 64-row tiles, heavy-first
    k_pv<<<dim3(D / 128, T / 64, B), 256, 0, stream>>>(
        Epk, Vt, out, RS, T, D);
}